// Round 1
// baseline (277.547 us; speedup 1.0000x reference)
//
#include <hip/hip_runtime.h>
#include <hip/hip_bf16.h>

typedef __attribute__((ext_vector_type(8))) __bf16 bf16x8;
typedef __attribute__((ext_vector_type(4))) __bf16 bf16x4;
typedef __attribute__((ext_vector_type(4))) float f32x4;

__device__ __forceinline__ void async_copy16(const void* gsrc, void* ldst) {
  __builtin_amdgcn_global_load_lds(
      (const __attribute__((address_space(1))) unsigned int*)(gsrc),
      (__attribute__((address_space(3))) unsigned int*)(ldst),
      16, 0, 0);
}

// ---------------------------------------------------------------------------
// GEMM: C[j] = act( A[j] (MxK) * W[j]^T (NxK, row-major N=512) + bias )
// LAYER 1: act = tanh           (a1)
// LAYER 2: act = sigmoid(tanh)  (+ extra tanh for net j==2, the z gate)
// Tile: 128x128, BK=32, 256 threads = 4 waves in 2x2, each wave 64x64.
// ---------------------------------------------------------------------------
template <int LAYER>
__global__ __launch_bounds__(256) void gemm_kernel(
    const __bf16* __restrict__ A,     // layer1: [M,512] shared; layer2: [3][M,512]
    const __bf16* __restrict__ W,     // [3][512][512] row-major (N,K)
    const float* __restrict__ bias,   // original [7][512] fp32, k = 2j+1
    __bf16* __restrict__ out)         // [3][M][512]
{
  constexpr int M  = 16384;
  constexpr int K  = 512;
  constexpr int BK = 32;

  const int j     = blockIdx.z;
  const int mbase = blockIdx.x * 128;
  const int nbase = blockIdx.y * 128;

  const __bf16* Aj = (LAYER == 2) ? (A + (size_t)j * M * K) : A;
  const __bf16* Wj = W + (size_t)j * 512 * K;

  __shared__ __align__(16) __bf16 As[128 * BK];
  __shared__ __align__(16) __bf16 Bs[128 * BK];

  const int tid  = threadIdx.x;
  const int wid  = tid >> 6;
  const int lane = tid & 63;
  const int wm   = (wid >> 1) * 64;       // wave m-offset in tile
  const int wn   = (wid & 1) * 64;        // wave n-offset in tile
  const int srow = wid * 16 + (lane >> 2);  // staging row within 64-row half
  const int scol = (lane & 3) * 8;          // staging col (elements)
  const int fr   = lane & 15;               // fragment m/n index
  const int q8   = (lane >> 4) * 8;         // fragment k offset

  f32x4 acc[4][4] = {};

  for (int k0 = 0; k0 < K; k0 += BK) {
    __syncthreads();  // previous tile's LDS reads complete before overwrite
#pragma unroll
    for (int r = 0; r < 2; ++r) {
      // lane l writes LDS base + 16*l; base is wave-uniform (wid only).
      async_copy16(Aj + (size_t)(mbase + r * 64 + srow) * K + (k0 + scol),
                   (void*)&As[(r * 64 + wid * 16) * BK]);
      async_copy16(Wj + (size_t)(nbase + r * 64 + srow) * K + (k0 + scol),
                   (void*)&Bs[(r * 64 + wid * 16) * BK]);
    }
    __syncthreads();  // drains vmcnt (global_load_lds) per barrier semantics

    bf16x8 af[4], bfr[4];
#pragma unroll
    for (int i = 0; i < 4; ++i) {
      af[i]  = *(const bf16x8*)&As[(wm + i * 16 + fr) * BK + q8];
      bfr[i] = *(const bf16x8*)&Bs[(wn + i * 16 + fr) * BK + q8];
    }
#pragma unroll
    for (int mi = 0; mi < 4; ++mi)
#pragma unroll
      for (int ni = 0; ni < 4; ++ni)
        acc[mi][ni] = __builtin_amdgcn_mfma_f32_16x16x32_bf16(
            af[mi], bfr[ni], acc[mi][ni], 0, 0, 0);
  }

  // Epilogue. C/D layout: col = lane&15, row = (lane>>4)*4 + reg.
  const int rowq = (lane >> 4) * 4;
#pragma unroll
  for (int ni = 0; ni < 4; ++ni) {
    const int col  = nbase + wn + ni * 16 + fr;
    const float bv = bias[(2 * j + 1) * 512 + col];
#pragma unroll
    for (int mi = 0; mi < 4; ++mi) {
#pragma unroll
      for (int r = 0; r < 4; ++r) {
        const int row = mbase + wm + mi * 16 + rowq + r;
        float v = acc[mi][ni][r] + bv;
        float res;
        if constexpr (LAYER == 1) {
          res = tanhf(v);
        } else {
          float g = 1.0f / (1.0f + __expf(-tanhf(v)));
          res = (j == 2) ? tanhf(g) : g;  // z = tanh(sigmoid(tanh(h2)))
        }
        out[(size_t)j * M * 512 + (size_t)row * 512 + col] = (__bf16)res;
      }
    }
  }
}

// cy2 = f2*cx2 + i2*z   gates = [i2 | f2 | z] bf16
__global__ __launch_bounds__(256) void final_kernel(
    const __bf16* __restrict__ gates, const float* __restrict__ cx2,
    float* __restrict__ out)
{
  constexpr size_t NH = (size_t)16384 * 512;
  const size_t i = ((size_t)blockIdx.x * 256 + threadIdx.x) * 4;
  bf16x4 i2 = *(const bf16x4*)&gates[i];
  bf16x4 f2 = *(const bf16x4*)&gates[NH + i];
  bf16x4 zz = *(const bf16x4*)&gates[2 * NH + i];
  f32x4 c = *(const f32x4*)&cx2[i];
  f32x4 r = __builtin_convertvector(f2, f32x4) * c +
            __builtin_convertvector(i2, f32x4) * __builtin_convertvector(zz, f32x4);
  *(f32x4*)&out[i] = r;
}

__global__ __launch_bounds__(256) void cvt_hx(const float* __restrict__ src,
                                              __bf16* __restrict__ dst)
{
  const size_t i = ((size_t)blockIdx.x * 256 + threadIdx.x) * 4;
  f32x4 v = *(const f32x4*)&src[i];
  *(bf16x4*)&dst[i] = __builtin_convertvector(v, bf16x4);
}

// pick k = 2j+1 from [7][512][512] -> [3][512][512] bf16
__global__ __launch_bounds__(256) void cvt_w(const float* __restrict__ src,
                                             __bf16* __restrict__ dst)
{
  const int j = blockIdx.y;
  const size_t i = ((size_t)blockIdx.x * 256 + threadIdx.x) * 4;
  f32x4 v = *(const f32x4*)&src[(size_t)(2 * j + 1) * 262144 + i];
  *(bf16x4*)&dst[(size_t)j * 262144 + i] = __builtin_convertvector(v, bf16x4);
}

extern "C" void kernel_launch(void* const* d_in, const int* in_sizes, int n_in,
                              void* d_out, int out_size, void* d_ws, size_t ws_size,
                              hipStream_t stream) {
  const float* hx  = (const float*)d_in[0];
  // d_in[1] = cx1 (dead: cy1 unused)
  const float* cx2 = (const float*)d_in[2];
  const float* W1  = (const float*)d_in[3];
  const float* b1  = (const float*)d_in[4];
  const float* W2  = (const float*)d_in[5];
  const float* b2  = (const float*)d_in[6];
  float* out = (float*)d_out;

  char* ws = (char*)d_ws;
  // layout (bytes):
  //   hxb   @ 0         : 16384*512*2       = 16,777,216
  //   W1b   @ 16777216  : 3*512*512*2       =  1,572,864
  //   W2b   @ 18350080  : 3*512*512*2       =  1,572,864
  //   a1    @ 19922944  : 3*16384*512*2     = 50,331,648
  //   gates @ 70254592  : 3*16384*512*2     = 50,331,648  (end 120,586,240)
  __bf16* hxb   = (__bf16*)(ws);
  __bf16* W1b   = (__bf16*)(ws + 16777216);
  __bf16* W2b   = (__bf16*)(ws + 18350080);
  __bf16* a1    = (__bf16*)(ws + 19922944);
  __bf16* gates = (__bf16*)(ws + 70254592);

  cvt_hx<<<8192, 256, 0, stream>>>(hx, hxb);                 // 16384*512/1024
  cvt_w<<<dim3(256, 3), 256, 0, stream>>>(W1, W1b);
  cvt_w<<<dim3(256, 3), 256, 0, stream>>>(W2, W2b);

  gemm_kernel<1><<<dim3(128, 4, 3), 256, 0, stream>>>(hxb, W1b, b1, a1);
  gemm_kernel<2><<<dim3(128, 4, 3), 256, 0, stream>>>(a1, W2b, b2, gates);

  final_kernel<<<8192, 256, 0, stream>>>(gates, cx2, out);
}